// Round 2
// baseline (2104.077 us; speedup 1.0000x reference)
//
#include <hip/hip_runtime.h>

// Problem: B=4, C=64, H=W=256, 4x4 tiles of 64, dynamic 3x3 conv 64->32 per tile.
// Inputs f32 (proven: bf16 decode of inputs NaN-poisoned round 1).
// Output f32. h (conv1 output) staged in f32 inside d_out planes (b*96 + c), c<64,
// then overwritten by the feature passthrough at the end of the launch.
//
// v3 conv core: round-1 counters showed VALU-issue = 228 us vs 123 us FMA floor
// on conv1 — consistent with UNFUSED mul+add (2x VALU). All inner products now
// use explicit fmaf(). Also: 32 oc per block (halves staging volume + LDS reads
// per FMA), tile 32x16, 2 px/thread, weights via wave-uniform SGPR loads
// (kw-sequenced, 16 live), LDS 20.7 KB/block for high occupancy.
// FC stack: B operand read directly from global per kk (L1/L2-resident weight
// panels) — removes the LDS-pipe oversubscription (2x b128 per 16 FMA).

// ---------------------------------------------------------------------------
// transpose rw1 [64oc][64ic][3][3] -> rw1t [4ocg][64ic][9k][16oc]
// ---------------------------------------------------------------------------
__global__ __launch_bounds__(256) void transp_rw1_k(
    const float* __restrict__ rw1, float* __restrict__ rt)
{
    int idx = blockIdx.x * 256 + threadIdx.x;
    if (idx >= 36864) return;
    int ocg = idx / 9216;
    int r   = idx - ocg * 9216;
    int ic  = r / 144;
    int r2  = r - ic * 144;
    int k   = r2 >> 4;
    int o   = r2 & 15;
    rt[idx] = rw1[(((size_t)(ocg * 16 + o) * 64 + ic) * 9) + k];
}

// ---------------------------------------------------------------------------
// 3x3 conv, 32 oc per block, 2 px per thread. Block 256 thr = 16x16,
// spatial tile 32(w) x 16(h). Weight layout [ocg16][ic64][k9][oc16].
// MODE 0: conv1  — in=feature, wt=rw1t, bias=rb1, leaky ReLU ->
//                  h planes in d_out at (b*96 + oc), oc<64. grid (8,16,8).
// MODE 1: dyncnv — in=feature, wt=wb (fc3 wrote transposed layout),
//                  bias from wb row tail -> planes (b*96+64+oc). grid (8,16,4).
// ---------------------------------------------------------------------------
template <int MODE>
__global__ __launch_bounds__(256, 4) void conv3x3_v3(
    const float* __restrict__ in,    // feature f32 [4][64][256][256]
    const float* __restrict__ wt,    // transposed weights (see above)
    const float* __restrict__ bbf,   // MODE0: rb1[64]; MODE1: wb (bias at row tail)
    float* __restrict__ outb)        // d_out f32 [4][96][256][256]
{
    __shared__ float sIn[8 * 18 * 36];   // 8 ic x 18 rows x (34 cols + 2 pad)

    const int bx = blockIdx.x, by = blockIdx.y, bz = blockIdx.z;
    int b, ocg;
    if (MODE == 0) { b = bz >> 1; ocg = bz & 1; }   // ocg selects oc 0..31 / 32..63
    else           { b = bz;      ocg = 0;      }
    const int tid = threadIdx.x;
    const int tx = tid & 15, ty = tid >> 4;
    const int x0 = bx * 32, y0 = by * 16;

    int bt = 0;
    const float* wbase;
    if (MODE == 0) {
        wbase = wt + (size_t)ocg * 2 * 9216;          // two 16-oc groups
    } else {
        bt = b * 16 + (by >> 2) * 4 + (bx >> 1);      // 64x64 weight-tile index
        wbase = wt + (size_t)bt * 18464;
    }

    float acc[2][32];   // [px][oc]
#pragma unroll
    for (int p = 0; p < 2; ++p)
#pragma unroll
        for (int oc = 0; oc < 32; ++oc) acc[p][oc] = 0.f;

    for (int cc = 0; cc < 8; ++cc) {   // 8 chunks of 8 input channels
        __syncthreads();
        // stage 8 ic x 18 x 34 halo tile (global zero-pad), LDS row stride 36
        for (int idx = tid; idx < 8 * 18 * 34; idx += 256) {
            int ic  = idx / 612;
            int rem = idx - ic * 612;
            int r   = rem / 34;
            int c   = rem - r * 34;
            int gy = y0 + r - 1, gx = x0 + c - 1;
            float v = 0.f;
            if ((unsigned)gy < 256u && (unsigned)gx < 256u)
                v = in[(((size_t)b * 64 + cc * 8 + ic) * 256 + gy) * 256 + gx];
            sIn[ic * 648 + r * 36 + c] = v;
        }
        __syncthreads();

        for (int ic = 0; ic < 8; ++ic) {
            const float* sI = &sIn[ic * 648 + ty * 36 + 2 * tx];
#pragma unroll
            for (int kh = 0; kh < 3; ++kh) {
                const float* rp = sI + kh * 36;
                float2 pa = *(const float2*)&rp[0];   // cols 2tx, 2tx+1
                float2 pb = *(const float2*)&rp[2];   // cols 2tx+2, 2tx+3
                float i0 = pa.x, i1 = pa.y, i2 = pb.x, i3 = pb.y;
#pragma unroll
                for (int oh = 0; oh < 2; ++oh) {
                    // wave-uniform weight pointer -> s_load
                    const float* wp = wbase + (size_t)oh * 9216
                                    + (cc * 8 + ic) * 144 + kh * 48;
#pragma unroll
                    for (int kw = 0; kw < 3; ++kw) {
                        float w[16];
                        *(float4*)&w[0]  = *(const float4*)&wp[kw * 16 + 0];
                        *(float4*)&w[4]  = *(const float4*)&wp[kw * 16 + 4];
                        *(float4*)&w[8]  = *(const float4*)&wp[kw * 16 + 8];
                        *(float4*)&w[12] = *(const float4*)&wp[kw * 16 + 12];
                        float ia = (kw == 0) ? i0 : (kw == 1) ? i1 : i2;
                        float ib = (kw == 0) ? i1 : (kw == 1) ? i2 : i3;
#pragma unroll
                        for (int o = 0; o < 16; ++o) {
                            acc[0][oh * 16 + o] = fmaf(ia, w[o], acc[0][oh * 16 + o]);
                            acc[1][oh * 16 + o] = fmaf(ib, w[o], acc[1][oh * 16 + o]);
                        }
                    }
                }
            }
        }
    }

    const int gy = y0 + ty;
#pragma unroll
    for (int oc = 0; oc < 32; ++oc) {
        float bv;
        int plane;
        if (MODE == 0) {
            bv = bbf[ocg * 32 + oc];
            plane = b * 96 + ocg * 32 + oc;
        } else {
            bv = bbf[(size_t)bt * 18464 + 18432 + oc];
            plane = b * 96 + 64 + oc;
        }
        float v0 = acc[0][oc] + bv;
        float v1 = acc[1][oc] + bv;
        if (MODE == 0) {
            v0 = (v0 >= 0.f) ? v0 : 0.2f * v0;   // leaky relu
            v1 = (v1 >= 0.f) ? v1 : 0.2f * v1;
        }
        size_t o = (((size_t)plane) * 256 + gy) * 256 + x0 + 2 * tx;
        float2 st = {v0, v1};
        *(float2*)&outb[o] = st;
    }
}

// ---------------------------------------------------------------------------
// conv2: 64 -> 1 channel, 3x3 pad 1, + bias + tanh. Reads f32 h from d_out
// planes (b*96 + ic). (fmaf'd; otherwise unchanged — small.)
// ---------------------------------------------------------------------------
__global__ __launch_bounds__(256) void conv2_tanh_k(
    const float* __restrict__ hin,   // d_out f32, h at planes b*96 + 0..63
    const float* __restrict__ rw2,   // [1][64][3][3]
    const float* __restrict__ rb2,   // [1]
    float* __restrict__ ad)          // adaptive f32 [4][256][256]
{
    __shared__ float sIn[16 * 18 * 35];
    __shared__ float sW[144];
    const int bx = blockIdx.x, by = blockIdx.y, b = blockIdx.z;
    const int tid = threadIdx.x;
    const int tx = tid & 15, ty = tid >> 4;
    const int x0 = bx * 32, y0 = by * 16;
    float a0 = 0.f, a1 = 0.f;

    for (int cc = 0; cc < 4; ++cc) {
        __syncthreads();
        for (int idx = tid; idx < 16 * 18 * 34; idx += 256) {
            int ic = idx / 612;
            int rem = idx - ic * 612;
            int row = rem / 34;
            int col = rem - row * 34;
            int gy = y0 + row - 1, gx = x0 + col - 1;
            float v = 0.f;
            if ((unsigned)gy < 256u && (unsigned)gx < 256u)
                v = hin[(((size_t)b * 96 + cc * 16 + ic) * 256 + gy) * 256 + gx];
            sIn[ic * 630 + row * 35 + col] = v;
        }
        if (tid < 144) sW[tid] = rw2[cc * 144 + tid];
        __syncthreads();

        for (int ic = 0; ic < 16; ++ic) {
            const float* sI = &sIn[ic * 630 + ty * 35 + tx];
            const float* sWi = &sW[ic * 9];
#pragma unroll
            for (int k = 0; k < 9; ++k) {
                const int kh = k / 3, kw = k - kh * 3;
                float w = sWi[k];
                a0 = fmaf(sI[kh * 35 + kw], w, a0);
                a1 = fmaf(sI[kh * 35 + kw + 16], w, a1);
            }
        }
    }
    float bias = rb2[0];
    size_t o = ((size_t)b * 256 + y0 + ty) * 256 + x0 + tx;
    ad[o] = tanhf(a0 + bias);
    ad[o + 16] = tanhf(a1 + bias);
}

// ---------------------------------------------------------------------------
// Adaptive-avg gram: per (bt, p, q) average the 66->32 window over the padded
// 66x66 tile of `adaptive`. Denominator counts pad zeros (matches reference).
// ---------------------------------------------------------------------------
__global__ __launch_bounds__(256) void gram_pool_k(
    const float* __restrict__ adaptive, float* __restrict__ gram)
{
    int idx = blockIdx.x * 256 + threadIdx.x;  // 64*1024
    int bt = idx >> 10;
    int pq = idx & 1023;
    int p = pq >> 5, q = pq & 31;
    int b = bt >> 4, t = bt & 15;
    int ti = t >> 2, tj = t & 3;
    int sp = (p * 33) >> 4, ep = ((p + 1) * 33 + 15) >> 4;  // 66/32 == 33/16
    int sq = (q * 33) >> 4, eq = ((q + 1) * 33 + 15) >> 4;
    float s = 0.f;
    for (int hh = sp; hh < ep; ++hh) {
        int gy = ti * 64 + hh - 1;
        if ((unsigned)gy >= 256u) continue;
        for (int w = sq; w < eq; ++w) {
            int gx = tj * 64 + w - 1;
            if ((unsigned)gx < 256u) s += adaptive[((size_t)b * 256 + gy) * 256 + gx];
        }
    }
    gram[idx] = s / (float)((ep - sp) * (eq - sq));
}

// ---------------------------------------------------------------------------
// FC: C[64,N] = act(A[64,K] @ B[K,N] + bias). All f32.
// Block computes a 64x64 tile of C; threads 16x16, 4x4 per thread.
// v2: B read directly from global per kk (weight panels are L1/L2-resident;
// removes the LDS-pipe oversubscription). Only A staged in LDS (4.4 KB).
// trans=1 (fc3): scatter the first 18432 cols of each row into the
// [ocg2][ic64][k9][oc16] layout conv3x3_v3<1> consumes; bias cols stay put.
// ---------------------------------------------------------------------------
__global__ __launch_bounds__(256) void fc_gemm_k(
    const float* __restrict__ A, const float* __restrict__ Bm,
    const float* __restrict__ bias, float* __restrict__ Cm,
    int K, int N, int act, int trans)
{
    __shared__ float As[16][68];  // [kk][m]
    const int n0 = blockIdx.x * 64;
    const int tid = threadIdx.x;
    const int tx = tid & 15, ty = tid >> 4;
    float acc[4][4];
#pragma unroll
    for (int i = 0; i < 4; ++i)
#pragma unroll
        for (int j = 0; j < 4; ++j) acc[i][j] = 0.f;

    const int mA = tid >> 2, kA = (tid & 3) * 4;

    // per-thread B column pointer (walks down rows of B across the whole K loop)
    const int gnb = n0 + tx * 4;
    const float* bp = Bm + (gnb + 3 < N ? gnb : 0);   // OOB threads read col 0; stores guarded

    for (int k0 = 0; k0 < K; k0 += 16) {
        __syncthreads();
        float4 av = *(const float4*)&A[(size_t)mA * K + k0 + kA];
        As[kA + 0][mA] = av.x;
        As[kA + 1][mA] = av.y;
        As[kA + 2][mA] = av.z;
        As[kA + 3][mA] = av.w;
        __syncthreads();
#pragma unroll
        for (int kk = 0; kk < 16; ++kk) {
            float4 bb = *(const float4*)bp;
            bp += N;
            float4 a = *(const float4*)&As[kk][ty * 4];
            acc[0][0] = fmaf(a.x, bb.x, acc[0][0]); acc[0][1] = fmaf(a.x, bb.y, acc[0][1]);
            acc[0][2] = fmaf(a.x, bb.z, acc[0][2]); acc[0][3] = fmaf(a.x, bb.w, acc[0][3]);
            acc[1][0] = fmaf(a.y, bb.x, acc[1][0]); acc[1][1] = fmaf(a.y, bb.y, acc[1][1]);
            acc[1][2] = fmaf(a.y, bb.z, acc[1][2]); acc[1][3] = fmaf(a.y, bb.w, acc[1][3]);
            acc[2][0] = fmaf(a.z, bb.x, acc[2][0]); acc[2][1] = fmaf(a.z, bb.y, acc[2][1]);
            acc[2][2] = fmaf(a.z, bb.z, acc[2][2]); acc[2][3] = fmaf(a.z, bb.w, acc[2][3]);
            acc[3][0] = fmaf(a.w, bb.x, acc[3][0]); acc[3][1] = fmaf(a.w, bb.y, acc[3][1]);
            acc[3][2] = fmaf(a.w, bb.z, acc[3][2]); acc[3][3] = fmaf(a.w, bb.w, acc[3][3]);
        }
    }
#pragma unroll
    for (int i = 0; i < 4; ++i) {
        int m = ty * 4 + i;
#pragma unroll
        for (int j = 0; j < 4; ++j) {
            int n = n0 + tx * 4 + j;
            if (n < N) {
                float v = acc[i][j] + bias[n];
                if (act) v = fmaxf(v, 0.f);
                int col = n;
                if (trans && n < 18432) {
                    int oc  = n / 576;
                    int rem = n - oc * 576;          // ic*9 + k
                    col = (oc >> 4) * 9216 + rem * 16 + (oc & 15);
                }
                Cm[(size_t)m * N + col] = v;
            }
        }
    }
}

// ---------------------------------------------------------------------------
// feature (f32) -> f32 passthrough into output channels 0..63 (plane remap).
// Runs LAST: overwrites the h staging planes.
// ---------------------------------------------------------------------------
__global__ __launch_bounds__(256) void copy_feat_k(
    const float4* __restrict__ f, float4* __restrict__ o)
{
    int idx = blockIdx.x * 256 + threadIdx.x;  // 4,194,304 float4
    int plane = idx >> 14;                     // b*64 + c (16384 f4 / plane)
    int off = idx & 16383;
    int b = plane >> 6, c = plane & 63;
    o[((size_t)(b * 96 + c)) * 16384 + off] = f[idx];
}

extern "C" void kernel_launch(void* const* d_in, const int* in_sizes, int n_in,
                              void* d_out, int out_size, void* d_ws, size_t ws_size,
                              hipStream_t stream) {
    const float* feature = (const float*)d_in[0];
    const float* rw1 = (const float*)d_in[1];
    const float* rb1 = (const float*)d_in[2];
    const float* rw2 = (const float*)d_in[3];
    const float* rb2 = (const float*)d_in[4];
    const float* fw1 = (const float*)d_in[5];
    const float* fb1 = (const float*)d_in[6];
    const float* fw2 = (const float*)d_in[7];
    const float* fb2 = (const float*)d_in[8];
    const float* fw3 = (const float*)d_in[9];
    const float* fb3 = (const float*)d_in[10];
    float* out = (float*)d_out;

    // Workspace layout (~7.1 MB):
    float* adaptive = (float*)d_ws;                   // 262,144 f32
    float* gram = adaptive + 262144;                  // 65,536 f32
    float* g1 = gram + 65536;                         // 131,072 f32
    float* g2 = g1 + 131072;                          // 131,072 f32
    float* wb = g2 + 131072;                          // 1,181,696 f32
    float* rw1t = g1;                                 // alias: dead before fc1 writes g1

    // 0. transpose rw1 -> [4ocg][64ic][9k][16oc] (rw1t aliases g1; conv1 reads
    //    it before fc1 overwrites g1 — stream-ordered, safe)
    transp_rw1_k<<<dim3(144), 256, 0, stream>>>(rw1, rw1t);
    // 1. conv1 + leaky relu -> h staged in d_out planes (b*96 + 0..63)
    conv3x3_v3<0><<<dim3(8, 16, 8), 256, 0, stream>>>(feature, rw1t, rb1, out);
    // 2. conv2 + tanh -> adaptive (reads h from d_out)
    conv2_tanh_k<<<dim3(8, 16, 4), 256, 0, stream>>>(out, rw2, rb2, adaptive);
    // 3. adaptive-avg gram -> gram [64][1024]
    gram_pool_k<<<dim3(256), 256, 0, stream>>>(adaptive, gram);
    // 4-6. FC stack -> wb [64][18464]; fc3 writes weight cols pre-transposed
    fc_gemm_k<<<dim3(32), 256, 0, stream>>>(gram, fw1, fb1, g1, 1024, 2048, 1, 0);
    fc_gemm_k<<<dim3(32), 256, 0, stream>>>(g1, fw2, fb2, g2, 2048, 2048, 1, 0);
    fc_gemm_k<<<dim3(289), 256, 0, stream>>>(g2, fw3, fb3, wb, 2048, 18464, 0, 1);
    // 7. dynamic per-tile conv -> out channels 64..95 (+ bias, spliced)
    conv3x3_v3<1><<<dim3(8, 16, 4), 256, 0, stream>>>(feature, wb, wb, out);
    // 8. passthrough: feature -> out channels 0..63 (overwrites h staging)
    copy_feat_k<<<dim3(16384), 256, 0, stream>>>((const float4*)feature, (float4*)out);
}

// Round 3
// 1455.785 us; speedup vs baseline: 1.4453x; 1.4453x over previous
//
#include <hip/hip_runtime.h>

// Problem: B=4, C=64, H=W=256, 4x4 tiles of 64, dynamic 3x3 conv 64->32 per tile.
// Inputs f32. Output f32. h (conv1 output) staged in d_out planes (b*96+c), c<64,
// then overwritten by the feature passthrough at the end of the launch.
//
// v4 fc pipeline: M=64 == wave size -> lane = m. Per kk: coalesced 4B/lane load
// of A_t[kk][lane], wave-uniform 64B of B row (s_load, scalar pipe), 16 fmaf.
// No LDS, no barriers. Stores are naturally transposed+coalesced = next layer's
// A_t. K-split (fc1 x4, fc2 x8) for occupancy + tiny reduce kernels. fc3 output
// (wb_t [18464][64]) converted to conv layout by an LDS-tiled fixup kernel.
// Round-2 lesson: global-B per kk at ~1 wave/SIMD is latency death (539 us);
// round-0/1 LDS design is LDS-pipe capped at 33% VALU (~92 us fc3 floor).

// ---------------------------------------------------------------------------
// transpose rw1 [64oc][64ic][3][3] -> rw1t [4ocg][64ic][9k][16oc]
// ---------------------------------------------------------------------------
__global__ __launch_bounds__(256) void transp_rw1_k(
    const float* __restrict__ rw1, float* __restrict__ rt)
{
    int idx = blockIdx.x * 256 + threadIdx.x;
    if (idx >= 36864) return;
    int ocg = idx / 9216;
    int r   = idx - ocg * 9216;
    int ic  = r / 144;
    int r2  = r - ic * 144;
    int k   = r2 >> 4;
    int o   = r2 & 15;
    rt[idx] = rw1[(((size_t)(ocg * 16 + o) * 64 + ic) * 9) + k];
}

// ---------------------------------------------------------------------------
// 3x3 conv, 32 oc per block, 2 px per thread. Block 256 thr = 16x16,
// spatial tile 32(w) x 16(h). Weight layout [ocg16][ic64][k9][oc16].
// (unchanged from round 2)
// ---------------------------------------------------------------------------
template <int MODE>
__global__ __launch_bounds__(256, 4) void conv3x3_v3(
    const float* __restrict__ in,    // feature f32 [4][64][256][256]
    const float* __restrict__ wt,    // transposed weights (see above)
    const float* __restrict__ bbf,   // MODE0: rb1[64]; MODE1: wbc (bias at row tail)
    float* __restrict__ outb)        // d_out f32 [4][96][256][256]
{
    __shared__ float sIn[8 * 18 * 36];   // 8 ic x 18 rows x (34 cols + 2 pad)

    const int bx = blockIdx.x, by = blockIdx.y, bz = blockIdx.z;
    int b, ocg;
    if (MODE == 0) { b = bz >> 1; ocg = bz & 1; }   // ocg selects oc 0..31 / 32..63
    else           { b = bz;      ocg = 0;      }
    const int tid = threadIdx.x;
    const int tx = tid & 15, ty = tid >> 4;
    const int x0 = bx * 32, y0 = by * 16;

    int bt = 0;
    const float* wbase;
    if (MODE == 0) {
        wbase = wt + (size_t)ocg * 2 * 9216;          // two 16-oc groups
    } else {
        bt = b * 16 + (by >> 2) * 4 + (bx >> 1);      // 64x64 weight-tile index
        wbase = wt + (size_t)bt * 18464;
    }

    float acc[2][32];   // [px][oc]
#pragma unroll
    for (int p = 0; p < 2; ++p)
#pragma unroll
        for (int oc = 0; oc < 32; ++oc) acc[p][oc] = 0.f;

    for (int cc = 0; cc < 8; ++cc) {   // 8 chunks of 8 input channels
        __syncthreads();
        // stage 8 ic x 18 x 34 halo tile (global zero-pad), LDS row stride 36
        for (int idx = tid; idx < 8 * 18 * 34; idx += 256) {
            int ic  = idx / 612;
            int rem = idx - ic * 612;
            int r   = rem / 34;
            int c   = rem - r * 34;
            int gy = y0 + r - 1, gx = x0 + c - 1;
            float v = 0.f;
            if ((unsigned)gy < 256u && (unsigned)gx < 256u)
                v = in[(((size_t)b * 64 + cc * 8 + ic) * 256 + gy) * 256 + gx];
            sIn[ic * 648 + r * 36 + c] = v;
        }
        __syncthreads();

        for (int ic = 0; ic < 8; ++ic) {
            const float* sI = &sIn[ic * 648 + ty * 36 + 2 * tx];
#pragma unroll
            for (int kh = 0; kh < 3; ++kh) {
                const float* rp = sI + kh * 36;
                float2 pa = *(const float2*)&rp[0];   // cols 2tx, 2tx+1
                float2 pb = *(const float2*)&rp[2];   // cols 2tx+2, 2tx+3
                float i0 = pa.x, i1 = pa.y, i2 = pb.x, i3 = pb.y;
#pragma unroll
                for (int oh = 0; oh < 2; ++oh) {
                    // wave-uniform weight pointer -> s_load
                    const float* wp = wbase + (size_t)oh * 9216
                                    + (cc * 8 + ic) * 144 + kh * 48;
#pragma unroll
                    for (int kw = 0; kw < 3; ++kw) {
                        float w[16];
                        *(float4*)&w[0]  = *(const float4*)&wp[kw * 16 + 0];
                        *(float4*)&w[4]  = *(const float4*)&wp[kw * 16 + 4];
                        *(float4*)&w[8]  = *(const float4*)&wp[kw * 16 + 8];
                        *(float4*)&w[12] = *(const float4*)&wp[kw * 16 + 12];
                        float ia = (kw == 0) ? i0 : (kw == 1) ? i1 : i2;
                        float ib = (kw == 0) ? i1 : (kw == 1) ? i2 : i3;
#pragma unroll
                        for (int o = 0; o < 16; ++o) {
                            acc[0][oh * 16 + o] = fmaf(ia, w[o], acc[0][oh * 16 + o]);
                            acc[1][oh * 16 + o] = fmaf(ib, w[o], acc[1][oh * 16 + o]);
                        }
                    }
                }
            }
        }
    }

    const int gy = y0 + ty;
#pragma unroll
    for (int oc = 0; oc < 32; ++oc) {
        float bv;
        int plane;
        if (MODE == 0) {
            bv = bbf[ocg * 32 + oc];
            plane = b * 96 + ocg * 32 + oc;
        } else {
            bv = bbf[(size_t)bt * 18464 + 18432 + oc];
            plane = b * 96 + 64 + oc;
        }
        float v0 = acc[0][oc] + bv;
        float v1 = acc[1][oc] + bv;
        if (MODE == 0) {
            v0 = (v0 >= 0.f) ? v0 : 0.2f * v0;   // leaky relu
            v1 = (v1 >= 0.f) ? v1 : 0.2f * v1;
        }
        size_t o = (((size_t)plane) * 256 + gy) * 256 + x0 + 2 * tx;
        float2 st = {v0, v1};
        *(float2*)&outb[o] = st;
    }
}

// ---------------------------------------------------------------------------
// conv2: 64 -> 1 channel, 3x3 pad 1, + bias + tanh. (unchanged)
// ---------------------------------------------------------------------------
__global__ __launch_bounds__(256) void conv2_tanh_k(
    const float* __restrict__ hin,   // d_out f32, h at planes b*96 + 0..63
    const float* __restrict__ rw2,   // [1][64][3][3]
    const float* __restrict__ rb2,   // [1]
    float* __restrict__ ad)          // adaptive f32 [4][256][256]
{
    __shared__ float sIn[16 * 18 * 35];
    __shared__ float sW[144];
    const int bx = blockIdx.x, by = blockIdx.y, b = blockIdx.z;
    const int tid = threadIdx.x;
    const int tx = tid & 15, ty = tid >> 4;
    const int x0 = bx * 32, y0 = by * 16;
    float a0 = 0.f, a1 = 0.f;

    for (int cc = 0; cc < 4; ++cc) {
        __syncthreads();
        for (int idx = tid; idx < 16 * 18 * 34; idx += 256) {
            int ic = idx / 612;
            int rem = idx - ic * 612;
            int row = rem / 34;
            int col = rem - row * 34;
            int gy = y0 + row - 1, gx = x0 + col - 1;
            float v = 0.f;
            if ((unsigned)gy < 256u && (unsigned)gx < 256u)
                v = hin[(((size_t)b * 96 + cc * 16 + ic) * 256 + gy) * 256 + gx];
            sIn[ic * 630 + row * 35 + col] = v;
        }
        if (tid < 144) sW[tid] = rw2[cc * 144 + tid];
        __syncthreads();

        for (int ic = 0; ic < 16; ++ic) {
            const float* sI = &sIn[ic * 630 + ty * 35 + tx];
            const float* sWi = &sW[ic * 9];
#pragma unroll
            for (int k = 0; k < 9; ++k) {
                const int kh = k / 3, kw = k - kh * 3;
                float w = sWi[k];
                a0 = fmaf(sI[kh * 35 + kw], w, a0);
                a1 = fmaf(sI[kh * 35 + kw + 16], w, a1);
            }
        }
    }
    float bias = rb2[0];
    size_t o = ((size_t)b * 256 + y0 + ty) * 256 + x0 + tx;
    ad[o] = tanhf(a0 + bias);
    ad[o + 16] = tanhf(a1 + bias);
}

// ---------------------------------------------------------------------------
// Adaptive-avg gram. v4: writes TRANSPOSED gram_t[pq][bt] (coalesced: lanes
// over bt) so fc1 can read it as A_t[k][m]. Wave-uniform pq -> uniform loop
// bounds (no divergence).
// ---------------------------------------------------------------------------
__global__ __launch_bounds__(256) void gram_pool_k(
    const float* __restrict__ adaptive, float* __restrict__ gram_t)
{
    int idx = blockIdx.x * 256 + threadIdx.x;  // 64*1024
    int bt = idx & 63;
    int pq = idx >> 6;
    int p = pq >> 5, q = pq & 31;
    int b = bt >> 4, t = bt & 15;
    int ti = t >> 2, tj = t & 3;
    int sp = (p * 33) >> 4, ep = ((p + 1) * 33 + 15) >> 4;  // 66/32 == 33/16
    int sq = (q * 33) >> 4, eq = ((q + 1) * 33 + 15) >> 4;
    float s = 0.f;
    for (int hh = sp; hh < ep; ++hh) {
        int gy = ti * 64 + hh - 1;
        if ((unsigned)gy >= 256u) continue;
        for (int w = sq; w < eq; ++w) {
            int gx = tj * 64 + w - 1;
            if ((unsigned)gx < 256u) s += adaptive[((size_t)b * 256 + gy) * 256 + gx];
        }
    }
    gram_t[(size_t)pq * 64 + bt] = s / (float)((ep - sp) * (eq - sq));
}

// ---------------------------------------------------------------------------
// fc stream: C[64][N] = A[64][K] @ B[K][N], lane = m (row), wave = 16 cols.
// A_t layout [K][64]. Per kk: 1 coalesced vector load (A) + 64B uniform scalar
// load (B row slice) + 16 fmaf. No LDS, no barriers.
// gridDim.y = K-split: partial (no bias/act) to out[ky][n][64].
// gridDim.y == 1: direct store with bias (+optional relu) to out[n][64].
// ---------------------------------------------------------------------------
__global__ __launch_bounds__(256) void fc_stream_k(
    const float* __restrict__ At, const float* __restrict__ Bm,
    const float* __restrict__ bias, float* __restrict__ out,
    int K, int N, int KC, int act)
{
    const int tid = threadIdx.x;
    const int lane = tid & 63;
    const int w = __builtin_amdgcn_readfirstlane(tid >> 6);
    const int n0w = blockIdx.x * 64 + w * 16;
    const bool valid = (n0w + 16 <= N);
    const int n0e = valid ? n0w : N - 16;            // clamp (fc3 tail); stores skipped

    const int k0 = blockIdx.y * KC;
    const int k1 = (k0 + KC < K) ? (k0 + KC) : K;

    float acc[16];
#pragma unroll
    for (int j = 0; j < 16; ++j) acc[j] = 0.f;

    const float* ap = At + (size_t)k0 * 64 + lane;
    const float* bp = Bm + (size_t)k0 * N + n0e;
#pragma unroll 4
    for (int kk = k0; kk < k1; ++kk) {
        float a = *ap;
        ap += 64;
        const float* br = bp;                        // wave-uniform -> s_load
        bp += N;
#pragma unroll
        for (int j = 0; j < 16; ++j) acc[j] = fmaf(a, br[j], acc[j]);
    }

    if (!valid) return;
    if (gridDim.y == 1) {
#pragma unroll
        for (int j = 0; j < 16; ++j) {
            float v = acc[j] + bias[n0w + j];
            if (act) v = fmaxf(v, 0.f);
            out[(size_t)(n0w + j) * 64 + lane] = v;   // transposed, coalesced
        }
    } else {
        float* po = out + ((size_t)blockIdx.y * N + n0w) * 64 + lane;
#pragma unroll
        for (int j = 0; j < 16; ++j) po[(size_t)j * 64] = acc[j];
    }
}

// ---------------------------------------------------------------------------
// reduce K-split partials: out_t[n][64] = act(sum_s part[s][n][64] + bias[n])
// ---------------------------------------------------------------------------
__global__ __launch_bounds__(256) void fc_reduce_k(
    const float* __restrict__ part, const float* __restrict__ bias,
    float* __restrict__ out, int S, int N, int act)
{
    int gid = blockIdx.x * 256 + threadIdx.x;        // float4 index over N*64/4
    const float4* p4 = (const float4*)part;
    float4 v = p4[gid];
    for (int s = 1; s < S; ++s) {
        float4 u = p4[(size_t)s * N * 16 + gid];
        v.x += u.x; v.y += u.y; v.z += u.z; v.w += u.w;
    }
    int n = gid >> 4;                                // 16 float4 per n-row
    float bv = bias[n];
    v.x += bv; v.y += bv; v.z += bv; v.w += bv;
    if (act) {
        v.x = fmaxf(v.x, 0.f); v.y = fmaxf(v.y, 0.f);
        v.z = fmaxf(v.z, 0.f); v.w = fmaxf(v.w, 0.f);
    }
    ((float4*)out)[gid] = v;
}

// ---------------------------------------------------------------------------
// wb fixup: wb_t [18464 n][64 bt] -> wbc [64 bt][18464] in conv layout:
// n = oc*576 + icks (oc<32)  ->  col = (oc>>4)*9216 + icks*16 + (oc&15)
// n = 18432 + oc (bias)      ->  col = 18432 + oc
// LDS-tiled: blocks 0..287 = (ocg, icks0/4); block 288 = bias rows.
// Both global phases fully coalesced (lanes over m on read, over col on write).
// ---------------------------------------------------------------------------
__global__ __launch_bounds__(256) void wbfix_k(
    const float* __restrict__ wbt, float* __restrict__ wbc)
{
    const int blk = blockIdx.x;
    const int tid = threadIdx.x;
    if (blk == 288) {   // bias rows
        for (int f = tid; f < 2048; f += 256) {
            int oc = f >> 6, m = f & 63;
            wbc[(size_t)m * 18464 + 18432 + oc] = wbt[(size_t)(18432 + oc) * 64 + m];
        }
        return;
    }
    __shared__ float s[64][65];
    const int ocg = blk / 144;
    const int icks0 = (blk - ocg * 144) * 4;
    const int m = tid & 63, grp = tid >> 6;
#pragma unroll
    for (int i = 0; i < 16; ++i) {
        int p = grp * 16 + i;                        // p = ickl*16 + oc
        int n = (ocg * 16 + (p & 15)) * 576 + icks0 + (p >> 4);
        s[p][m] = wbt[(size_t)n * 64 + m];           // lanes over m: coalesced
    }
    __syncthreads();
    const int pp = tid & 63;
#pragma unroll
    for (int i = 0; i < 16; ++i) {
        int mm = grp * 16 + i;
        wbc[(size_t)mm * 18464 + ocg * 9216 + icks0 * 16 + pp] = s[pp][mm];
    }
}

// ---------------------------------------------------------------------------
// feature -> out channels 0..63 passthrough (plane remap). Runs LAST.
// ---------------------------------------------------------------------------
__global__ __launch_bounds__(256) void copy_feat_k(
    const float4* __restrict__ f, float4* __restrict__ o)
{
    int idx = blockIdx.x * 256 + threadIdx.x;  // 4,194,304 float4
    int plane = idx >> 14;                     // b*64 + c (16384 f4 / plane)
    int off = idx & 16383;
    int b = plane >> 6, c = plane & 63;
    o[((size_t)(b * 96 + c)) * 16384 + off] = f[idx];
}

extern "C" void kernel_launch(void* const* d_in, const int* in_sizes, int n_in,
                              void* d_out, int out_size, void* d_ws, size_t ws_size,
                              hipStream_t stream) {
    const float* feature = (const float*)d_in[0];
    const float* rw1 = (const float*)d_in[1];
    const float* rb1 = (const float*)d_in[2];
    const float* rw2 = (const float*)d_in[3];
    const float* rb2 = (const float*)d_in[4];
    const float* fw1 = (const float*)d_in[5];
    const float* fb1 = (const float*)d_in[6];
    const float* fw2 = (const float*)d_in[7];
    const float* fb2 = (const float*)d_in[8];
    const float* fw3 = (const float*)d_in[9];
    const float* fb3 = (const float*)d_in[10];
    float* out = (float*)d_out;

    // Workspace layout (11.8 MB, all f32 counts):
    float* adaptive = (float*)d_ws;                   //   262,144
    float* gram_t = adaptive + 262144;                //    65,536  [1024 k][64 m]
    float* g1_t = gram_t + 65536;                     //   131,072  [2048][64]
    float* g2_t = g1_t + 131072;                      //   131,072  [2048][64]
    float* wb_t = g2_t + 131072;                      // 1,181,696  [18464][64]
    float* wbc  = wb_t + 1181696;                     // 1,181,696  [64][18464]
    // aliases of wb_t region (lifetimes strictly before fc3's store):
    float* rw1t = wb_t;                               // 36,864; dead after conv1
    float* part = wb_t;                               // <=1,048,576; dead after reduce

    // 0. transpose rw1 -> [4ocg][64ic][9k][16oc]
    transp_rw1_k<<<dim3(144), 256, 0, stream>>>(rw1, rw1t);
    // 1. conv1 + leaky relu -> h staged in d_out planes (b*96 + 0..63)
    conv3x3_v3<0><<<dim3(8, 16, 8), 256, 0, stream>>>(feature, rw1t, rb1, out);
    // 2. conv2 + tanh -> adaptive
    conv2_tanh_k<<<dim3(8, 16, 4), 256, 0, stream>>>(out, rw2, rb2, adaptive);
    // 3. adaptive-avg gram -> gram_t [1024][64]
    gram_pool_k<<<dim3(256), 256, 0, stream>>>(adaptive, gram_t);
    // 4. fc1: K=1024 split x4 -> partials -> g1_t (relu)
    fc_stream_k<<<dim3(32, 4), 256, 0, stream>>>(gram_t, fw1, fb1, part, 1024, 2048, 256, 1);
    fc_reduce_k<<<dim3(128), 256, 0, stream>>>(part, fb1, g1_t, 4, 2048, 1);
    // 5. fc2: K=2048 split x8 -> partials -> g2_t (relu)
    fc_stream_k<<<dim3(32, 8), 256, 0, stream>>>(g1_t, fw2, fb2, part, 2048, 2048, 256, 1);
    fc_reduce_k<<<dim3(128), 256, 0, stream>>>(part, fb2, g2_t, 8, 2048, 1);
    // 6. fc3: direct (bias, no act) -> wb_t [18464][64]
    fc_stream_k<<<dim3(289, 1), 256, 0, stream>>>(g2_t, fw3, fb3, wb_t, 2048, 18464, 2048, 0);
    // 7. wb_t -> wbc (conv-consumable [64][2ocg*9216 + 32bias])
    wbfix_k<<<dim3(289), 256, 0, stream>>>(wb_t, wbc);
    // 8. dynamic per-tile conv -> out channels 64..95
    conv3x3_v3<1><<<dim3(8, 16, 4), 256, 0, stream>>>(feature, wbc, wbc, out);
    // 9. passthrough: feature -> out channels 0..63
    copy_feat_k<<<dim3(16384), 256, 0, stream>>>((const float4*)feature, (float4*)out);
}